// Round 3
// baseline (379.199 us; speedup 1.0000x reference)
//
#include <hip/hip_runtime.h>
#include <math.h>

// 4-qubit, 2-layer RY + CNOT-ring quantum layer, batched over 4.19M rows.
// Strategy: memory-bound streaming kernel. Gate-by-gate state evolution in
// registers (CNOTs = compile-time permutations), normalization folded out via
// orthogonality of U, trig precomputed once into d_ws.

#define BATCH   4194304
#define BLOCKS  4096
#define TPB     256

// ---- prep: cs[0..7] = cos(w/2), cs[8..15] = sin(w/2)  (w is [2][4] flat) ----
__global__ void prep_cs_kernel(const float* __restrict__ w, float* __restrict__ cs) {
    int i = threadIdx.x;
    if (i < 8) {
        float h = 0.5f * w[i];
        cs[i]     = cosf(h);
        cs[i + 8] = sinf(h);
    }
}

__global__ __launch_bounds__(TPB) void qlayer_kernel(
        const float4* __restrict__ x,
        const float*  __restrict__ cs,
        float4*       __restrict__ out) {
    // Uniform loads -> scalar (SGPR) broadcast; no per-lane cost.
    float C[8], S[8];
#pragma unroll
    for (int i = 0; i < 8; ++i) { C[i] = cs[i]; S[i] = cs[i + 8]; }

    const int nthreads = BLOCKS * TPB;
    int g = blockIdx.x * TPB + threadIdx.x;

    for (int r = g; r < BATCH; r += nthreads) {
        const float4* xp = x + (size_t)r * 4;
        float4 v0 = xp[0], v1 = xp[1], v2 = xp[2], v3 = xp[3];
        float a[16] = { v0.x, v0.y, v0.z, v0.w,  v1.x, v1.y, v1.z, v1.w,
                        v2.x, v2.y, v2.z, v2.w,  v3.x, v3.y, v3.z, v3.w };

#pragma unroll
        for (int l = 0; l < 2; ++l) {
            // --- RY on each wire (wire 0 = MSB = bit 3) ---
#pragma unroll
            for (int w = 0; w < 4; ++w) {
                const int m = 8 >> w;
                float c = C[l * 4 + w], s = S[l * 4 + w];
#pragma unroll
                for (int b = 0; b < 16; ++b) {
                    if (!(b & m)) {
                        float lo = a[b], hi = a[b | m];
                        a[b]     = c * lo - s * hi;
                        a[b | m] = s * lo + c * hi;
                    }
                }
            }
            // --- CNOT ring (0,1),(1,2),(2,3),(3,0): control/target wire ->
            // bit positions (3,2),(2,1),(1,0),(0,3). Each is an involutive
            // permutation: a'[b] = a[b ^ (bit_c(b) ? mask_t : 0)].
            {
                float t[16];
#pragma unroll
                for (int b = 0; b < 16; ++b) t[b] = a[b ^ (((b >> 3) & 1) ? 4 : 0)];
#pragma unroll
                for (int b = 0; b < 16; ++b) a[b] = t[b];
#pragma unroll
                for (int b = 0; b < 16; ++b) t[b] = a[b ^ (((b >> 2) & 1) ? 2 : 0)];
#pragma unroll
                for (int b = 0; b < 16; ++b) a[b] = t[b];
#pragma unroll
                for (int b = 0; b < 16; ++b) t[b] = a[b ^ (((b >> 1) & 1) ? 1 : 0)];
#pragma unroll
                for (int b = 0; b < 16; ++b) a[b] = t[b];
#pragma unroll
                for (int b = 0; b < 16; ++b) t[b] = a[b ^ (((b >> 0) & 1) ? 8 : 0)];
#pragma unroll
                for (int b = 0; b < 16; ++b) a[b] = t[b];
            }
        }

        // probs (unnormalized) and PauliZ expvals.
        float p[16];
#pragma unroll
        for (int b = 0; b < 16; ++b) p[b] = a[b] * a[b];

        float T = 0.f;
#pragma unroll
        for (int b = 0; b < 16; ++b) T += p[b];

        float S0 = 0.f, S1 = 0.f, S2 = 0.f, S3 = 0.f;
#pragma unroll
        for (int b = 0; b < 16; ++b) {
            if ((b >> 3) & 1) S0 += p[b];
            if ((b >> 2) & 1) S1 += p[b];
            if ((b >> 1) & 1) S2 += p[b];
            if ((b >> 0) & 1) S3 += p[b];
        }

        float invT = 1.0f / T;   // U orthogonal => T == ||x||^2
        out[r] = make_float4(1.f - 2.f * S0 * invT,
                             1.f - 2.f * S1 * invT,
                             1.f - 2.f * S2 * invT,
                             1.f - 2.f * S3 * invT);
    }
}

extern "C" void kernel_launch(void* const* d_in, const int* in_sizes, int n_in,
                              void* d_out, int out_size, void* d_ws, size_t ws_size,
                              hipStream_t stream) {
    const float* x  = (const float*)d_in[0];   // [BATCH,16] f32
    const float* w  = (const float*)d_in[1];   // [2,4] f32
    float*       cs = (float*)d_ws;            // 16 floats scratch
    float4*      o4 = (float4*)d_out;          // [BATCH,4] f32

    prep_cs_kernel<<<1, 64, 0, stream>>>(w, cs);
    qlayer_kernel<<<BLOCKS, TPB, 0, stream>>>((const float4*)x, cs, o4);
}

// Round 9
// 377.485 us; speedup vs baseline: 1.0045x; 1.0045x over previous
//
#include <hip/hip_runtime.h>
#include <math.h>

// 4-qubit, 2-layer RY + CNOT-ring quantum layer, 4.19M rows.
// Half-row cooperative layout: lane pair (2j,2j+1) owns row j; lane parity p
// holds the bit3(=wire0) half of the 16-state vector (8 amplitudes in regs).
// Loads: 2 consecutive float4 per lane -> 32B lane stride (2 line-touches vs 4).
// Stores: float2 per lane, perfectly unit-stride.
// Wire0 gates go through __shfl_xor(.,1); wires 1-3 stay in-register.
// Normalization folded out (U orthogonal => T = ||x||^2).

#define BATCH   4194304
#define BLOCKS  4096
#define TPB     256
#define PAIRS_PER_PASS (BLOCKS * (TPB / 2))

// cs[0..7] = cos(w/2), cs[8..15] = sin(w/2)   (w flat [2][4])
__global__ void prep_cs_kernel(const float* __restrict__ w, float* __restrict__ cs) {
    int i = threadIdx.x;
    if (i < 8) {
        float h = 0.5f * w[i];
        cs[i]     = cosf(h);
        cs[i + 8] = sinf(h);
    }
}

// in-register butterfly: (lo,hi) <- (c*lo - s*hi, s*lo + c*hi)
#define BFLY(lo, hi, c, s) do {                     \
        float _l = (lo), _h = (hi);                 \
        (lo) = fmaf(-(s), _h, (c) * _l);            \
        (hi) = fmaf( (s), _l, (c) * _h);            \
    } while (0)

__global__ __launch_bounds__(TPB) void qlayer_kernel(
        const float4* __restrict__ x4,
        const float*  __restrict__ cs,
        float2*       __restrict__ out2) {
    // Uniform (scalar) broadcast of the 16 trig constants.
    float C[8], S[8];
#pragma unroll
    for (int i = 0; i < 8; ++i) { C[i] = cs[i]; S[i] = cs[i + 8]; }

    const int gid = blockIdx.x * TPB + threadIdx.x;
    const int p   = gid & 1;                 // this lane's bit3 (wire0) value
    const float sgn = p ? 1.0f : -1.0f;      // cross-lane RY sign

    for (int r = (gid >> 1); r < BATCH; r += PAIRS_PER_PASS) {
        // lane's 8 amplitudes: states b = 8p + v, v = 0..7
        const float4 lo4 = x4[(size_t)r * 4 + 2 * p];
        const float4 hi4 = x4[(size_t)r * 4 + 2 * p + 1];
        float a0 = lo4.x, a1 = lo4.y, a2 = lo4.z, a3 = lo4.w;
        float a4 = hi4.x, a5 = hi4.y, a6 = hi4.z, a7 = hi4.w;

#pragma unroll
        for (int l = 0; l < 2; ++l) {
            const float c0 = C[4*l+0], s0 = S[4*l+0];
            const float c1 = C[4*l+1], s1 = S[4*l+1];
            const float c2 = C[4*l+2], s2 = S[4*l+2];
            const float c3 = C[4*l+3], s3 = S[4*l+3];

            // RY wire0 (bit3, cross-lane): a = c*a + sgn*s*partner
            {
                const float ss = sgn * s0;
                float b0 = __shfl_xor(a0, 1), b1 = __shfl_xor(a1, 1);
                float b2 = __shfl_xor(a2, 1), b3 = __shfl_xor(a3, 1);
                float b4 = __shfl_xor(a4, 1), b5 = __shfl_xor(a5, 1);
                float b6 = __shfl_xor(a6, 1), b7 = __shfl_xor(a7, 1);
                a0 = fmaf(ss, b0, c0 * a0); a1 = fmaf(ss, b1, c0 * a1);
                a2 = fmaf(ss, b2, c0 * a2); a3 = fmaf(ss, b3, c0 * a3);
                a4 = fmaf(ss, b4, c0 * a4); a5 = fmaf(ss, b5, c0 * a5);
                a6 = fmaf(ss, b6, c0 * a6); a7 = fmaf(ss, b7, c0 * a7);
            }
            // RY wire1 (bit2): pairs (v, v+4)
            BFLY(a0, a4, c1, s1); BFLY(a1, a5, c1, s1);
            BFLY(a2, a6, c1, s1); BFLY(a3, a7, c1, s1);
            // RY wire2 (bit1): (0,2),(1,3),(4,6),(5,7)
            BFLY(a0, a2, c2, s2); BFLY(a1, a3, c2, s2);
            BFLY(a4, a6, c2, s2); BFLY(a5, a7, c2, s2);
            // RY wire3 (bit0): (0,1),(2,3),(4,5),(6,7)
            BFLY(a0, a1, c3, s3); BFLY(a2, a3, c3, s3);
            BFLY(a4, a5, c3, s3); BFLY(a6, a7, c3, s3);

            // CNOT(0,1): control bit3 (=p), target bit2 -> p==1 lanes swap halves
            {
                float n0 = p ? a4 : a0, n4 = p ? a0 : a4;
                float n1 = p ? a5 : a1, n5 = p ? a1 : a5;
                float n2 = p ? a6 : a2, n6 = p ? a2 : a6;
                float n3 = p ? a7 : a3, n7 = p ? a3 : a7;
                a0 = n0; a1 = n1; a2 = n2; a3 = n3;
                a4 = n4; a5 = n5; a6 = n6; a7 = n7;
            }
            // CNOT(1,2): control bit2, target bit1 -> swap a4<->a6, a5<->a7 (free)
            { float t = a4; a4 = a6; a6 = t; t = a5; a5 = a7; a7 = t; }
            // CNOT(2,3): control bit1, target bit0 -> swap a2<->a3, a6<->a7 (free)
            { float t = a2; a2 = a3; a3 = t; t = a6; a6 = a7; a7 = t; }
            // CNOT(3,0): control bit0, target bit3 -> odd-v amps exchange lanes
            a1 = __shfl_xor(a1, 1); a3 = __shfl_xor(a3, 1);
            a5 = __shfl_xor(a5, 1); a7 = __shfl_xor(a7, 1);
        }

        // probabilities (unnormalized) and PauliZ expvals
        const float q0 = a0*a0, q1 = a1*a1, q2 = a2*a2, q3 = a3*a3;
        const float q4 = a4*a4, q5 = a5*a5, q6 = a6*a6, q7 = a7*a7;

        const float Tloc = ((q0+q1)+(q2+q3)) + ((q4+q5)+(q6+q7));
        const float PT   = __shfl_xor(Tloc, 1);
        const float T    = Tloc + PT;               // == ||x||^2 (U orthogonal)

        const float S0 = p ? Tloc : PT;             // bit3 set == hi lane's total
        float s1l = (q4+q5)+(q6+q7);                // bit2 set
        float s2l = (q2+q3)+(q6+q7);                // bit1 set
        float s3l = (q1+q3)+(q5+q7);                // bit0 set
        const float S1 = s1l + __shfl_xor(s1l, 1);
        const float S2 = s2l + __shfl_xor(s2l, 1);
        const float S3 = s3l + __shfl_xor(s3l, 1);

        const float invT = 1.0f / T;
        const float o0 = 1.0f - 2.0f * S0 * invT;
        const float o1 = 1.0f - 2.0f * S1 * invT;
        const float o2 = 1.0f - 2.0f * S2 * invT;
        const float o3 = 1.0f - 2.0f * S3 * invT;

        // pair writes the row's float4 as two unit-stride float2 stores
        out2[(size_t)2 * r + p] = p ? make_float2(o2, o3) : make_float2(o0, o1);
    }
}

extern "C" void kernel_launch(void* const* d_in, const int* in_sizes, int n_in,
                              void* d_out, int out_size, void* d_ws, size_t ws_size,
                              hipStream_t stream) {
    const float* x  = (const float*)d_in[0];   // [BATCH,16] f32
    const float* w  = (const float*)d_in[1];   // [2,4] f32
    float*       cs = (float*)d_ws;            // 16 floats scratch
    float2*      o2 = (float2*)d_out;          // [BATCH,4] f32 as float2 pairs

    prep_cs_kernel<<<1, 64, 0, stream>>>(w, cs);
    qlayer_kernel<<<BLOCKS, TPB, 0, stream>>>((const float4*)x, cs, o2);
}